// Round 1
// baseline (167.191 us; speedup 1.0000x reference)
//
#include <hip/hip_runtime.h>

// RotMat forward: 511 rounds of 256 disjoint Givens rotations on rows of a
// [512, 1024] fp32 matrix (round-robin tournament schedule).
//
// Position-space formulation: position k always pairs with position 511-k;
// between rounds the values undergo a fixed cyclic shift (v[0] fixed,
// v[p]->v[p+1] for p=1..510, v[511]->v[1]). After 511 shifts the permutation
// is the identity, so the final store is by row index directly.
//
// Layout: 1 column per wave (64 lanes), lane l owns pairs k=4l..4l+3:
// lo[m] = v[4l+m], hi[m] = v[511-4l-m]. Rotation is lane-local; the shift is
// 2 shuffles + register renames + edge fixups at lanes 0/63. No LDS, no
// barriers in the main loop.

#define N_ROWS   512
#define N_COLS   1024
#define R_ROUNDS 511
#define PAIRS    256

// Precompute cs[r*256+k] = (cos(th), +-sin(th)) where the sign is + if the
// lo position's player is the lower row index i, else -.
__global__ __launch_bounds__(256) void rotmat_setup(const float* __restrict__ thetas,
                                                    float2* __restrict__ cs) {
    const int r = blockIdx.x;   // 0..510
    const int k = threadIdx.x;  // 0..255
    // player at position p in round r: p==0 -> 0 else ((p-1-r) mod 511)+1
    int pu = (k == 0) ? 0 : ((k - 1 - r + 1022) % 511) + 1;
    int pv = ((510 - k - r + 1022) % 511) + 1;
    int i = min(pu, pv), j = max(pu, pv);
    int t = i * 511 - (i * (i - 1)) / 2 + (j - i - 1);
    float s, c;
    sincosf(thetas[t], &s, &c);
    float sp = (pu < pv) ? s : -s;
    cs[r * PAIRS + k] = make_float2(c, sp);
}

#define ROT(mi, C, S)                                   \
    {                                                   \
        float L = lo[mi], H = hi[mi];                   \
        lo[mi] = fmaf((C), L, -(S) * H);                \
        hi[mi] = fmaf((C), H, (S) * L);                 \
    }

#define SHIFT()                                                   \
    {                                                             \
        float up   = __shfl_up(lo[3], 1);                         \
        float dn   = __shfl_down(hi[0], 1);                       \
        float nlo0 = (lane == 0) ? lo[0] : up;                    \
        float nlo1 = (lane == 0) ? hi[0] : lo[0];                 \
        float nhi3 = (lane == 63) ? lo[3] : dn;                   \
        lo[3] = lo[2]; lo[2] = lo[1]; lo[1] = nlo1; lo[0] = nlo0; \
        hi[0] = hi[1]; hi[1] = hi[2]; hi[2] = hi[3]; hi[3] = nhi3;\
    }

template <bool TAB>
__global__ __launch_bounds__(256) void rotmat_main(const float* __restrict__ x,
                                                   const float* __restrict__ thetas,
                                                   const float2* __restrict__ cs,
                                                   float* __restrict__ out) {
    const int lane = threadIdx.x & 63;
    const int wave = threadIdx.x >> 6;
    const int col  = (blockIdx.x << 2) + wave;  // one column per wave
    const int k0   = lane << 2;                 // first pair index of this lane

    float lo[4], hi[4];
#pragma unroll
    for (int m = 0; m < 4; ++m) {
        lo[m] = x[(k0 + m) * N_COLS + col];
        hi[m] = x[(511 - k0 - m) * N_COLS + col];
    }

    if constexpr (TAB) {
        // 128 float4 per round; lane reads 2 consecutive float4 (32B).
        const float4* csp = reinterpret_cast<const float4*>(cs) + (lane << 1);
        float4 a = csp[0], b = csp[1];  // round 0
        csp += 128;
        for (int r = 0; r < R_ROUNDS; ++r) {
            // prefetch next round (r=510 reads the padded 512th round; unused)
            float4 an = csp[0], bn = csp[1];
            csp += 128;
            ROT(0, a.x, a.y)
            ROT(1, a.z, a.w)
            ROT(2, b.x, b.y)
            ROT(3, b.z, b.w)
            SHIFT()
            a = an; b = bn;
        }
    } else {
        // Fallback: compute schedule + sincos inline (no workspace table).
        int pu[4], pv[4];
#pragma unroll
        for (int m = 0; m < 4; ++m) {
            pu[m] = (k0 + m == 0) ? 0 : (k0 + m);
            pv[m] = 511 - (k0 + m);
        }
        for (int r = 0; r < R_ROUNDS; ++r) {
#pragma unroll
            for (int m = 0; m < 4; ++m) {
                int i = min(pu[m], pv[m]), j = max(pu[m], pv[m]);
                int t = i * 511 - (i * (i - 1)) / 2 + (j - i - 1);
                float s, c;
                sincosf(thetas[t], &s, &c);
                float sp = (pu[m] < pv[m]) ? s : -s;
                ROT(m, c, sp)
            }
            SHIFT()
#pragma unroll
            for (int m = 0; m < 4; ++m) {
                pu[m] = (k0 + m == 0) ? 0 : ((pu[m] == 1) ? 511 : pu[m] - 1);
                pv[m] = (pv[m] == 1) ? 511 : pv[m] - 1;
            }
        }
    }

    // After 511 shifts the position->row permutation is identity.
#pragma unroll
    for (int m = 0; m < 4; ++m) {
        out[(k0 + m) * N_COLS + col]       = lo[m];
        out[(511 - k0 - m) * N_COLS + col] = hi[m];
    }
}

extern "C" void kernel_launch(void* const* d_in, const int* in_sizes, int n_in,
                              void* d_out, int out_size, void* d_ws, size_t ws_size,
                              hipStream_t stream) {
    const float* x  = (const float*)d_in[0];
    const float* th = (const float*)d_in[1];
    float* out      = (float*)d_out;

    // Table: 512 rounds padded (prefetch reads one past the last round).
    const size_t need = (size_t)512 * PAIRS * sizeof(float2);  // 1 MiB
    if (ws_size >= need) {
        float2* cs = (float2*)d_ws;
        rotmat_setup<<<R_ROUNDS, PAIRS, 0, stream>>>(th, cs);
        rotmat_main<true><<<N_COLS / 4, 256, 0, stream>>>(x, th, cs, out);
    } else {
        rotmat_main<false><<<N_COLS / 4, 256, 0, stream>>>(x, th, nullptr, out);
    }
}

// Round 2
// 71.601 us; speedup vs baseline: 2.3350x; 2.3350x over previous
//
#include <hip/hip_runtime.h>

// RotMat forward: 511 rounds of 256 disjoint Givens rotations on rows of a
// [512, 1024] fp32 matrix (round-robin tournament schedule).
//
// Position-space formulation: position k always pairs with position 511-k;
// between rounds the values undergo a fixed cyclic shift (v[0] fixed,
// v[p]->v[p+1] for p=1..510, v[511]->v[1]). After 511 shifts the permutation
// is the identity, so the final store is by row index directly.
//
// Layout: 1 column per wave (64 lanes), lane l owns pairs k=4l..4l+3.
// R1 change: 16-round register ring buffer for the cos/sin table (fully
// unrolled, static indices) so the leading wave has 32 loads in flight
// instead of paying ~900cy HBM latency per round (R0: 830 cy/round measured).

#define N_ROWS   512
#define N_COLS   1024
#define R_ROUNDS 511
#define PAIRS    256
#define DEPTH    16

// Precompute cs[r*256+k] = (cos(th), +-sin(th)) where the sign is + if the
// lo position's player is the lower row index i, else -.
__global__ __launch_bounds__(256) void rotmat_setup(const float* __restrict__ thetas,
                                                    float2* __restrict__ cs) {
    const int r = blockIdx.x;   // 0..510
    const int k = threadIdx.x;  // 0..255
    // player at position p in round r: p==0 -> 0 else ((p-1-r) mod 511)+1
    int pu = (k == 0) ? 0 : ((k - 1 - r + 1022) % 511) + 1;
    int pv = ((510 - k - r + 1022) % 511) + 1;
    int i = min(pu, pv), j = max(pu, pv);
    int t = i * 511 - (i * (i - 1)) / 2 + (j - i - 1);
    float s, c;
    sincosf(thetas[t], &s, &c);
    float sp = (pu < pv) ? s : -s;
    cs[r * PAIRS + k] = make_float2(c, sp);
}

#define ROT(mi, C, S)                                   \
    {                                                   \
        float L = lo[mi], H = hi[mi];                   \
        lo[mi] = fmaf((C), L, -(S) * H);                \
        hi[mi] = fmaf((C), H, (S) * L);                 \
    }

#define SHIFT()                                                   \
    {                                                             \
        float up   = __shfl_up(lo[3], 1);                         \
        float dn   = __shfl_down(hi[0], 1);                       \
        float nlo0 = (lane == 0) ? lo[0] : up;                    \
        float nlo1 = (lane == 0) ? hi[0] : lo[0];                 \
        float nhi3 = (lane == 63) ? lo[3] : dn;                   \
        lo[3] = lo[2]; lo[2] = lo[1]; lo[1] = nlo1; lo[0] = nlo0; \
        hi[0] = hi[1]; hi[1] = hi[2]; hi[2] = hi[3]; hi[3] = nhi3;\
    }

#define ROUND(AA, BB)            \
    ROT(0, (AA).x, (AA).y)       \
    ROT(1, (AA).z, (AA).w)       \
    ROT(2, (BB).x, (BB).y)       \
    ROT(3, (BB).z, (BB).w)       \
    SHIFT()

template <bool TAB>
__global__ __launch_bounds__(256) void rotmat_main(const float* __restrict__ x,
                                                   const float* __restrict__ thetas,
                                                   const float2* __restrict__ cs,
                                                   float* __restrict__ out) {
    const int lane = threadIdx.x & 63;
    const int wave = threadIdx.x >> 6;
    const int col  = (blockIdx.x << 2) + wave;  // one column per wave
    const int k0   = lane << 2;                 // first pair index of this lane

    float lo[4], hi[4];
#pragma unroll
    for (int m = 0; m < 4; ++m) {
        lo[m] = x[(k0 + m) * N_COLS + col];
        hi[m] = x[(511 - k0 - m) * N_COLS + col];
    }

    if constexpr (TAB) {
        // Per round: 128 float4; this lane's two are at float4 index
        // lane*2, lane*2+1. Ring buffer of DEPTH rounds, fully unrolled.
        const float4* base = reinterpret_cast<const float4*>(cs) + (lane << 1);
        float4 A[DEPTH], B[DEPTH];
#pragma unroll
        for (int u = 0; u < DEPTH; ++u) {
            A[u] = base[u * 128];
            B[u] = base[u * 128 + 1];
        }
        // 31 blocks of 16 rounds = rounds 0..495; loads issued for rounds
        // 16..511 (table padded to 512 rounds; round 511 loaded, unused).
        for (int rb = 0; rb < 496; rb += DEPTH) {
#pragma unroll
            for (int u = 0; u < DEPTH; ++u) {
                ROUND(A[u], B[u])
                A[u] = base[(rb + DEPTH + u) * 128];
                B[u] = base[(rb + DEPTH + u) * 128 + 1];
            }
        }
        // Remainder: rounds 496..510 from A[0..14] (loaded at rb=480).
#pragma unroll
        for (int u = 0; u < DEPTH - 1; ++u) {
            ROUND(A[u], B[u])
        }
    } else {
        // Fallback: compute schedule + sincos inline (no workspace table).
        int pu[4], pv[4];
#pragma unroll
        for (int m = 0; m < 4; ++m) {
            pu[m] = (k0 + m == 0) ? 0 : (k0 + m);
            pv[m] = 511 - (k0 + m);
        }
        for (int r = 0; r < R_ROUNDS; ++r) {
#pragma unroll
            for (int m = 0; m < 4; ++m) {
                int i = min(pu[m], pv[m]), j = max(pu[m], pv[m]);
                int t = i * 511 - (i * (i - 1)) / 2 + (j - i - 1);
                float s, c;
                sincosf(thetas[t], &s, &c);
                float sp = (pu[m] < pv[m]) ? s : -s;
                ROT(m, c, sp)
            }
            SHIFT()
#pragma unroll
            for (int m = 0; m < 4; ++m) {
                pu[m] = (k0 + m == 0) ? 0 : ((pu[m] == 1) ? 511 : pu[m] - 1);
                pv[m] = (pv[m] == 1) ? 511 : pv[m] - 1;
            }
        }
    }

    // After 511 shifts the position->row permutation is identity.
#pragma unroll
    for (int m = 0; m < 4; ++m) {
        out[(k0 + m) * N_COLS + col]       = lo[m];
        out[(511 - k0 - m) * N_COLS + col] = hi[m];
    }
}

extern "C" void kernel_launch(void* const* d_in, const int* in_sizes, int n_in,
                              void* d_out, int out_size, void* d_ws, size_t ws_size,
                              hipStream_t stream) {
    const float* x  = (const float*)d_in[0];
    const float* th = (const float*)d_in[1];
    float* out      = (float*)d_out;

    // Table: 512 rounds padded (pipeline reads one past the last round).
    const size_t need = (size_t)512 * PAIRS * sizeof(float2);  // 1 MiB
    if (ws_size >= need) {
        float2* cs = (float2*)d_ws;
        rotmat_setup<<<R_ROUNDS, PAIRS, 0, stream>>>(th, cs);
        rotmat_main<true><<<N_COLS / 4, 256, 0, stream>>>(x, th, cs, out);
    } else {
        rotmat_main<false><<<N_COLS / 4, 256, 0, stream>>>(x, th, nullptr, out);
    }
}